// Round 5
// baseline (516.014 us; speedup 1.0000x reference)
//
#include <hip/hip_runtime.h>

// GCN autoencoder: N=50000, E=800000, 128 -> 16 -> 128.
// Round 5: (a) range-scan CSR fill — per-block LDS cursors, dense writes into
// the block's own CSR slice (kills the 52 MB scattered-write amplification of
// R4's fill_kernel); (b) wave-per-node gather with shuffle reduction;
// (c) dinv fused into scan_final.

#define N_NODES 50000
#define N_EDGES 800000
#define D_IN    128
#define D_H     16
#define SCAN_B  256
#define N_CHUNK ((N_NODES + SCAN_B - 1) / SCAN_B)   // 196
#define FB      256                                  // fill blocks
#define NPB     ((N_NODES + FB - 1) / FB)            // 196 nodes per fill block

// ---- degree histogram on dst ----
__global__ void deg_int_kernel(const int* __restrict__ dst, int* __restrict__ degi) {
    int e = blockIdx.x * blockDim.x + threadIdx.x;
    if (e < N_EDGES) atomicAdd(&degi[dst[e]], 1);
}

// ---- exclusive scan of degi -> row_off (3 phases), dinv fused into final ----
__global__ void scan_partial(const int* __restrict__ degi, int* __restrict__ part) {
    __shared__ int s[SCAN_B];
    int tid = threadIdx.x;
    int idx = blockIdx.x * SCAN_B + tid;
    s[tid] = idx < N_NODES ? degi[idx] : 0;
    __syncthreads();
    for (int off = 128; off > 0; off >>= 1) {
        if (tid < off) s[tid] += s[tid + off];
        __syncthreads();
    }
    if (tid == 0) part[blockIdx.x] = s[0];
}

__global__ void scan_spine(int* __restrict__ part, int* __restrict__ row_off) {
    __shared__ int s[SCAN_B];
    int tid = threadIdx.x;
    int v = tid < N_CHUNK ? part[tid] : 0;
    s[tid] = v;
    __syncthreads();
    for (int off = 1; off < SCAN_B; off <<= 1) {
        int t = tid >= off ? s[tid - off] : 0;
        __syncthreads();
        s[tid] += t;
        __syncthreads();
    }
    part[tid] = s[tid] - v;  // exclusive
    if (tid == 0) row_off[N_NODES] = N_EDGES;
}

__global__ void scan_final(const int* __restrict__ degi, const int* __restrict__ part,
                           int* __restrict__ row_off, float* __restrict__ dinv) {
    __shared__ int s[SCAN_B];
    int tid = threadIdx.x;
    int idx = blockIdx.x * SCAN_B + tid;
    int v = idx < N_NODES ? degi[idx] : 0;
    s[tid] = v;
    __syncthreads();
    for (int off = 1; off < SCAN_B; off <<= 1) {
        int t = tid >= off ? s[tid - off] : 0;
        __syncthreads();
        s[tid] += t;
        __syncthreads();
    }
    if (idx < N_NODES) {
        row_off[idx] = part[blockIdx.x] + s[tid] - v;
        dinv[idx] = rsqrtf((float)v + 1.0f);   // +1 self loop
    }
}

// ---- range-scan CSR fill: block b owns nodes [b*NPB, b*NPB+NPB).
// Streams all dst (int4), LDS cursors, dense writes into own CSR slice. ----
__global__ void fill_scan(const int* __restrict__ src, const int* __restrict__ dst,
                          const int* __restrict__ row_off, int* __restrict__ edge_src) {
    __shared__ int cur[NPB];
    int n0 = blockIdx.x * NPB;
    int cnt = N_NODES - n0; if (cnt > NPB) cnt = NPB;
    for (int i = threadIdx.x; i < cnt; i += FB) cur[i] = row_off[n0 + i];
    __syncthreads();
    const int4* dst4 = (const int4*)dst;
    for (int q = threadIdx.x; q < N_EDGES / 4; q += FB) {
        int4 d = dst4[q];
        int e = q * 4;
        if ((unsigned)(d.x - n0) < (unsigned)cnt) edge_src[atomicAdd(&cur[d.x - n0], 1)] = src[e];
        if ((unsigned)(d.y - n0) < (unsigned)cnt) edge_src[atomicAdd(&cur[d.y - n0], 1)] = src[e + 1];
        if ((unsigned)(d.z - n0) < (unsigned)cnt) edge_src[atomicAdd(&cur[d.z - n0], 1)] = src[e + 2];
        if ((unsigned)(d.w - n0) < (unsigned)cnt) edge_src[atomicAdd(&cur[d.w - n0], 1)] = src[e + 3];
    }
}

// ---- h1 = x @ W1 ----
__global__ void h1_kernel(const float* __restrict__ x, const float* __restrict__ W1,
                          float* __restrict__ h1) {
    __shared__ float w1s[D_IN * D_H];  // 8 KB
    int tid = threadIdx.x;
    for (int i = tid; i < D_IN * D_H; i += 256) w1s[i] = W1[i];
    __syncthreads();

    int idx = blockIdx.x * 256 + tid;
    if (idx >= N_NODES * D_H) return;
    int row = idx >> 4;
    int col = idx & 15;
    const float4* xr = (const float4*)(x + row * D_IN);
    float acc = 0.0f;
    #pragma unroll
    for (int k4 = 0; k4 < D_IN / 4; ++k4) {
        float4 v = xr[k4];
        acc += v.x * w1s[(k4 * 4 + 0) * D_H + col];
        acc += v.y * w1s[(k4 * 4 + 1) * D_H + col];
        acc += v.z * w1s[(k4 * 4 + 2) * D_H + col];
        acc += v.w * w1s[(k4 * 4 + 3) * D_H + col];
    }
    h1[idx] = acc;
}

// ---- wave-per-node CSR gather:
// out[i,ch] = di*( di*feat[i,ch] + sum_p dinv[s]*feat[s,ch] ) + bias[ch]
// 64 lanes = 16 channels x 4 parallel edges; shuffle-reduce sub-partials. ----
__global__ void gather_kernel(const float* __restrict__ feat, const int* __restrict__ row_off,
                              const int* __restrict__ edge_src, const float* __restrict__ dinv,
                              const float* __restrict__ bias, float* __restrict__ outf) {
    int node = (blockIdx.x * blockDim.x + threadIdx.x) >> 6;  // one wave per node
    if (node >= N_NODES) return;
    int lane = threadIdx.x & 63;
    int ch = lane & 15;
    int sub = lane >> 4;     // 0..3
    float di = dinv[node];
    float acc = (sub == 0) ? feat[node * D_H + ch] * di : 0.0f;
    int p0 = row_off[node], p1 = row_off[node + 1];
    for (int p = p0 + sub; p < p1; p += 4) {
        int s = edge_src[p];
        acc += feat[s * D_H + ch] * dinv[s];
    }
    acc += __shfl_xor(acc, 16);
    acc += __shfl_xor(acc, 32);
    acc *= di;
    if (bias) acc += bias[ch];
    if (sub == 0) outf[node * D_H + ch] = acc;
}

// ---- out = agg2 @ W2 + b2 ----
__global__ void out_kernel(const float* __restrict__ agg2, const float* __restrict__ W2,
                           const float* __restrict__ b2, float* __restrict__ out) {
    int idx = blockIdx.x * blockDim.x + threadIdx.x;   // over N*32 float4 groups
    if (idx >= N_NODES * (D_IN / 4)) return;
    int row = idx >> 5;
    int j4 = idx & 31;
    const float* ar = agg2 + row * D_H;
    float4 acc = ((const float4*)b2)[j4];
    #pragma unroll
    for (int c = 0; c < D_H; ++c) {
        float a = ar[c];
        float4 w = ((const float4*)(W2 + c * D_IN))[j4];
        acc.x += a * w.x; acc.y += a * w.y; acc.z += a * w.z; acc.w += a * w.w;
    }
    ((float4*)(out))[idx] = acc;
}

extern "C" void kernel_launch(void* const* d_in, const int* in_sizes, int n_in,
                              void* d_out, int out_size, void* d_ws, size_t ws_size,
                              hipStream_t stream) {
    const float* x  = (const float*)d_in[0];
    const int*   ei = (const int*)d_in[1];   // [2, E]: src then dst
    const float* W1 = (const float*)d_in[2];
    const float* b1 = (const float*)d_in[3];
    const float* W2 = (const float*)d_in[4];
    const float* b2 = (const float*)d_in[5];
    float* out = (float*)d_out;

    const int* src = ei;
    const int* dst = ei + N_EDGES;

    // ws carve (all 4-byte elems)
    char* base = (char*)d_ws;
    int*   degi     = (int*)base;                 base += ((N_NODES + 3) & ~3) * 4;
    int*   row_off  = (int*)base;                 base += ((N_NODES + 1 + 3) & ~3) * 4;
    int*   part     = (int*)base;                 base += SCAN_B * 4;
    int*   edge_src = (int*)base;                 base += N_EDGES * 4;
    float* dinv     = (float*)base;               base += ((N_NODES + 3) & ~3) * 4;
    float* h1       = (float*)base;               base += N_NODES * D_H * 4;
    float* z        = (float*)base;               base += N_NODES * D_H * 4;
    float* agg2     = (float*)base;               base += N_NODES * D_H * 4;

    hipMemsetAsync(degi, 0, N_NODES * sizeof(int), stream);

    deg_int_kernel<<<(N_EDGES + 255) / 256, 256, 0, stream>>>(dst, degi);

    scan_partial<<<N_CHUNK, SCAN_B, 0, stream>>>(degi, part);
    scan_spine<<<1, SCAN_B, 0, stream>>>(part, row_off);
    scan_final<<<N_CHUNK, SCAN_B, 0, stream>>>(degi, part, row_off, dinv);

    fill_scan<<<FB, FB, 0, stream>>>(src, dst, row_off, edge_src);

    h1_kernel<<<(N_NODES * D_H + 255) / 256, 256, 0, stream>>>(x, W1, h1);

    // encoder: z = Agg(h1) + b1   (one wave per node)
    gather_kernel<<<(N_NODES * 64 + 255) / 256, 256, 0, stream>>>(h1, row_off, edge_src, dinv, b1, z);
    // decoder: agg2 = Agg(z)
    gather_kernel<<<(N_NODES * 64 + 255) / 256, 256, 0, stream>>>(z, row_off, edge_src, dinv, nullptr, agg2);

    out_kernel<<<(N_NODES * 32 + 255) / 256, 256, 0, stream>>>(agg2, W2, b2, out);
}

// Round 6
// 263.339 us; speedup vs baseline: 1.9595x; 1.9595x over previous
//
#include <hip/hip_runtime.h>

// GCN autoencoder: N=50000, E=800000, 128 -> 16 -> 128.
// Round 6: radix-bucket the edge list by dst range (256 buckets x 196 nodes),
// then per-bucket LDS fp32 accumulation for both GCN aggregations.
// - No CSR, no scan, no global deg histogram (degree counted per-bucket in LDS).
// - Device-scope atomics eliminated except 65k line-padded reservation adds.
// - Decoder aggregation + W2 GEMM + b2 fused; writes d_out directly.
// R5 lesson: keep edge-parallelism; never stream the whole edge list per block.

#define N_NODES 50000
#define N_EDGES 800000
#define D_IN    128
#define D_H     16
#define K_BUCK  256
#define NPB2    196      // nodes per bucket: bucket = dst / 196 (max 49999/196 = 255)
#define BCAP    4096     // slots per bucket; mean 3125, sigma ~56 -> 17 sigma margin
#define H1_BLKS 3125     // 50000*16/256
#define PA_BLKS 256
#define PA_CHUNK 3125    // 800000/256
#define GC_PAD  16       // gcur stride in ints (64 B) to avoid same-line atomic pileup

// ---- K1: fused [h1 GEMM] + [phase A bucket scatter] ----
__global__ __launch_bounds__(256) void k1_fused(
        const int* __restrict__ src, const int* __restrict__ dst,
        const float* __restrict__ x, const float* __restrict__ W1,
        int* __restrict__ gcur, float* __restrict__ h1, int* __restrict__ arr) {
    __shared__ float w1s[D_IN * D_H];   // used by h1 segment
    __shared__ int hist[K_BUCK];        // used by phase A segment
    __shared__ int cur[K_BUCK];
    int bid = blockIdx.x;
    int tid = threadIdx.x;

    if (bid < H1_BLKS) {
        // ---- h1 = x @ W1 ----
        for (int i = tid; i < D_IN * D_H; i += 256) w1s[i] = W1[i];
        __syncthreads();
        int idx = bid * 256 + tid;               // < 800000 exactly
        int row = idx >> 4;
        int col = idx & 15;
        const float4* xr = (const float4*)(x + row * D_IN);
        float acc = 0.0f;
        #pragma unroll
        for (int k4 = 0; k4 < D_IN / 4; ++k4) {
            float4 v = xr[k4];
            acc += v.x * w1s[(k4 * 4 + 0) * D_H + col];
            acc += v.y * w1s[(k4 * 4 + 1) * D_H + col];
            acc += v.z * w1s[(k4 * 4 + 2) * D_H + col];
            acc += v.w * w1s[(k4 * 4 + 3) * D_H + col];
        }
        h1[idx] = acc;
    } else {
        // ---- phase A: bucket scatter of packed (src<<8 | local_dst) ----
        int pb = bid - H1_BLKS;                  // 0..255
        int e0 = pb * PA_CHUNK;
        hist[tid] = 0;
        __syncthreads();
        for (int i = tid; i < PA_CHUNK; i += 256) {
            int d = dst[e0 + i];
            atomicAdd(&hist[d / NPB2], 1);
        }
        __syncthreads();
        // reserve a dense run in bucket tid
        cur[tid] = (tid << 12) + atomicAdd(&gcur[tid * GC_PAD], hist[tid]);
        __syncthreads();
        for (int i = tid; i < PA_CHUNK; i += 256) {
            int d = dst[e0 + i];
            int s = src[e0 + i];
            int b = d / NPB2;
            int pos = atomicAdd(&cur[b], 1);
            if (pos < ((b + 1) << 12))           // overflow guard (never in practice)
                arr[pos] = (s << 8) | (d - b * NPB2);
        }
    }
}

// ---- K2: per-bucket degree -> dinv, then scale h1 -> h1s = h1*dinv in place ----
__global__ __launch_bounds__(256) void k2_deg_scale(
        const int* __restrict__ arr, const int* __restrict__ gcur,
        float* __restrict__ h1, float* __restrict__ dinv) {
    __shared__ int cnt[NPB2];
    __shared__ float sdi[NPB2];
    int k = blockIdx.x, tid = threadIdx.x;
    for (int i = tid; i < NPB2; i += 256) cnt[i] = 0;
    __syncthreads();
    int count = min(gcur[k * GC_PAD], BCAP);
    int base = k << 12;
    for (int i = tid; i < count; i += 256) atomicAdd(&cnt[arr[base + i] & 255], 1);
    __syncthreads();
    int n0 = k * NPB2;
    int ncnt = min(NPB2, N_NODES - n0);
    for (int i = tid; i < ncnt; i += 256) {
        float di = rsqrtf((float)cnt[i] + 1.0f);   // +1 = self loop
        sdi[i] = di;
        dinv[n0 + i] = di;
    }
    __syncthreads();
    for (int g = tid; g < ncnt * 4; g += 256) {    // float4 groups over the node range
        int i = g >> 2;
        float di = sdi[i];
        float4* p = (float4*)(h1 + (n0 + i) * D_H);
        float4 v = p[g & 3];
        v.x *= di; v.y *= di; v.z *= di; v.w *= di;
        p[g & 3] = v;
    }
}

// ---- K3: encoder aggregation: zs[i] = di*( di*(h1s[i] + S h1s[s]) + b1 ) ----
__global__ __launch_bounds__(1024) void k3_agg_enc(
        const float* __restrict__ feat_s, const int* __restrict__ arr,
        const int* __restrict__ gcur, const float* __restrict__ dinv,
        const float* __restrict__ b1, float* __restrict__ zs) {
    __shared__ float acc[NPB2 * D_H];   // 12.25 KB
    int k = blockIdx.x, tid = threadIdx.x;
    for (int i = tid; i < NPB2 * D_H; i += 1024) acc[i] = 0.0f;
    __syncthreads();
    int count = min(gcur[k * GC_PAD], BCAP);
    int base = k << 12;
    int ch = tid & 15;
    for (int i = tid >> 4; i < count; i += 64) {
        int p = arr[base + i];
        atomicAdd(&acc[(p & 255) * D_H + ch], feat_s[(p >> 8) * D_H + ch]);
    }
    __syncthreads();
    int n0 = k * NPB2;
    int ncnt = min(NPB2, N_NODES - n0);
    for (int idx = tid; idx < ncnt * D_H; idx += 1024) {
        int i = n0 + (idx >> 4);
        int c = idx & 15;
        float di = dinv[i];
        float tot = acc[idx] + feat_s[i * D_H + c];
        zs[i * D_H + c] = di * (di * tot + b1[c]);
    }
}

// ---- K4: decoder aggregation fused with W2 GEMM + b2; writes out directly ----
__global__ __launch_bounds__(1024) void k4_agg_dec_out(
        const float* __restrict__ zs, const int* __restrict__ arr,
        const int* __restrict__ gcur, const float* __restrict__ dinv,
        const float* __restrict__ W2, const float* __restrict__ b2,
        float* __restrict__ out) {
    __shared__ float acc[NPB2 * D_H];   // 12.25 KB
    __shared__ float w2s[D_H * D_IN];   // 8 KB
    int k = blockIdx.x, tid = threadIdx.x;
    for (int i = tid; i < NPB2 * D_H; i += 1024) acc[i] = 0.0f;
    for (int i = tid; i < D_H * D_IN; i += 1024) w2s[i] = W2[i];
    __syncthreads();
    int count = min(gcur[k * GC_PAD], BCAP);
    int base = k << 12;
    int ch = tid & 15;
    for (int i = tid >> 4; i < count; i += 64) {
        int p = arr[base + i];
        atomicAdd(&acc[(p & 255) * D_H + ch], zs[(p >> 8) * D_H + ch]);
    }
    __syncthreads();
    int n0 = k * NPB2;
    int ncnt = min(NPB2, N_NODES - n0);
    // agg2 in place: acc = di*(acc + zs_self)
    for (int idx = tid; idx < ncnt * D_H; idx += 1024) {
        int i = n0 + (idx >> 4);
        float di = dinv[i];
        acc[idx] = di * (acc[idx] + zs[i * D_H + (idx & 15)]);
    }
    __syncthreads();
    // out[n][j] = sum_c acc[n][c]*W2[c][j] + b2[j]
    for (int idx = tid; idx < ncnt * D_IN; idx += 1024) {
        int n = idx >> 7;
        int j = idx & 127;
        const float* a = &acc[n * D_H];
        float v = b2[j];
        #pragma unroll
        for (int c = 0; c < D_H; ++c) v += a[c] * w2s[c * D_IN + j];
        out[(n0 + n) * D_IN + j] = v;
    }
}

extern "C" void kernel_launch(void* const* d_in, const int* in_sizes, int n_in,
                              void* d_out, int out_size, void* d_ws, size_t ws_size,
                              hipStream_t stream) {
    const float* x  = (const float*)d_in[0];
    const int*   ei = (const int*)d_in[1];   // [2, E]: src then dst (int32 per harness)
    const float* W1 = (const float*)d_in[2];
    const float* b1 = (const float*)d_in[3];
    const float* W2 = (const float*)d_in[4];
    const float* b2 = (const float*)d_in[5];
    float* out = (float*)d_out;

    const int* src = ei;
    const int* dst = ei + N_EDGES;

    // ws carve: gcur[256*16] | dinv[N] | h1[N*16] | zs[N*16] | arr[256*4096]  (~10.9 MB)
    char* base = (char*)d_ws;
    int*   gcur = (int*)base;                  base += K_BUCK * GC_PAD * 4;
    float* dinv = (float*)base;                base += N_NODES * 4;
    float* h1   = (float*)base;                base += N_NODES * D_H * 4;
    float* zs   = (float*)base;                base += N_NODES * D_H * 4;
    int*   arr  = (int*)base;                  base += K_BUCK * BCAP * 4;

    hipMemsetAsync(gcur, 0, K_BUCK * GC_PAD * sizeof(int), stream);

    k1_fused<<<H1_BLKS + PA_BLKS, 256, 0, stream>>>(src, dst, x, W1, gcur, h1, arr);
    k2_deg_scale<<<K_BUCK, 256, 0, stream>>>(arr, gcur, h1, dinv);
    k3_agg_enc<<<K_BUCK, 1024, 0, stream>>>(h1, arr, gcur, dinv, b1, zs);
    k4_agg_dec_out<<<K_BUCK, 1024, 0, stream>>>(zs, arr, gcur, dinv, W2, b2, out);
}